// Round 1
// baseline (2813.435 us; speedup 1.0000x reference)
//
#include <hip/hip_runtime.h>
#include <math.h>

#define N_TOT 32768
#define M_NBR 12
#define ORIG  92
#define EDGE  41
#define FD    128
#define HD    256
#define APC   256   // atoms per crystal
#define NCRY  128   // crystals (batch)

__device__ __forceinline__ float softplus_f(float x) {
    // log1p(exp(x)) stable form
    return fmaxf(x, 0.0f) + log1pf(expf(-fabsf(x)));
}
__device__ __forceinline__ float sigmoid_f(float x) {
    return 1.0f / (1.0f + expf(-x));
}

// ---------------- embed: x = atom_fea @ W_embed + b_embed ----------------
__global__ __launch_bounds__(64) void embed_kernel(
    const float* __restrict__ atom_fea, const float* __restrict__ W,
    const float* __restrict__ b, float* __restrict__ x)
{
    __shared__ float row[ORIG];
    const int n = blockIdx.x;
    const int t = threadIdx.x;           // 0..63
    const float* af = atom_fea + (long)n * ORIG;
    if (t < ORIG) row[t] = af[t];
    if (t + 64 < ORIG) row[t + 64] = af[t + 64];
    __syncthreads();

    const int f0 = t, f1 = t + 64;
    float acc0 = b[f0], acc1 = b[f1];
    #pragma unroll 4
    for (int k = 0; k < ORIG; ++k) {
        const float xk = row[k];
        acc0 = fmaf(xk, W[k * FD + f0], acc0);
        acc1 = fmaf(xk, W[k * FD + f1], acc1);
    }
    x[(long)n * FD + f0] = acc0;
    x[(long)n * FD + f1] = acc1;
}

// ---------------- one conv layer, fully fused per atom ----------------
// block = 64 threads = 1 wave; thread owns features f0=t, f1=t+64
__global__ __launch_bounds__(64) void conv_kernel(
    const float* __restrict__ x_in, float* __restrict__ x_out,
    const float* __restrict__ nbr_fea, const int* __restrict__ nbr_idx,
    const float* __restrict__ Wc, const float* __restrict__ bc,
    const float* __restrict__ Wn, const float* __restrict__ bn,
    const float* __restrict__ We, const float* __restrict__ be,
    const float* __restrict__ Wg, const float* __restrict__ bg,
    const float* __restrict__ Wm, const float* __restrict__ bm,
    const float* __restrict__ lns, const float* __restrict__ lnb)
{
    __shared__ float xc_s[FD];
    __shared__ float xg_s[M_NBR][FD];
    __shared__ float e_s[M_NBR][EDGE];
    __shared__ float inter_s[M_NBR][FD];
    __shared__ int   idx_s[M_NBR];

    const int n = blockIdx.x;
    const int t = threadIdx.x;           // 0..63
    const int f0 = t, f1 = t + 64;

    if (t < M_NBR) idx_s[t] = nbr_idx[n * M_NBR + t];
    xc_s[f0] = x_in[(long)n * FD + f0];
    xc_s[f1] = x_in[(long)n * FD + f1];
    {
        const float* ef = nbr_fea + (long)n * (M_NBR * EDGE);
        #pragma unroll
        for (int i = t; i < M_NBR * EDGE; i += 64)
            e_s[i / EDGE][i % EDGE] = ef[i];
    }
    __syncthreads();
    #pragma unroll
    for (int m = 0; m < M_NBR; ++m) {
        const long base = (long)idx_s[m] * FD;
        xg_s[m][f0] = x_in[base + f0];
        xg_s[m][f1] = x_in[base + f1];
    }
    __syncthreads();

    // ---- phi_c and phi_n GEMV phase ----
    float accC0 = bc[f0], accC1 = bc[f1];
    float accN0[M_NBR], accN1[M_NBR];
    #pragma unroll
    for (int m = 0; m < M_NBR; ++m) { accN0[m] = 0.f; accN1[m] = 0.f; }

    for (int k0 = 0; k0 < FD; k0 += 4) {
        const float4 xc4 = *(const float4*)(xc_s + k0);
        float wc0[4], wc1[4], wn0[4], wn1[4];
        #pragma unroll
        for (int j = 0; j < 4; ++j) {
            const float* wcp = Wc + (long)(k0 + j) * FD;
            const float* wnp = Wn + (long)(k0 + j) * FD;
            wc0[j] = wcp[f0]; wc1[j] = wcp[f1];
            wn0[j] = wnp[f0]; wn1[j] = wnp[f1];
        }
        const float xck[4] = {xc4.x, xc4.y, xc4.z, xc4.w};
        #pragma unroll
        for (int j = 0; j < 4; ++j) {
            accC0 = fmaf(xck[j], wc0[j], accC0);
            accC1 = fmaf(xck[j], wc1[j], accC1);
        }
        #pragma unroll
        for (int m = 0; m < M_NBR; ++m) {
            const float4 xg4 = *(const float4*)(xg_s[m] + k0);
            const float xv[4] = {xg4.x, xg4.y, xg4.z, xg4.w};
            #pragma unroll
            for (int j = 0; j < 4; ++j) {
                accN0[m] = fmaf(xv[j], wn0[j], accN0[m]);
                accN1[m] = fmaf(xv[j], wn1[j], accN1[m]);
            }
        }
    }

    // ---- phi_e GEMV phase (K = 41) ----
    float accE0[M_NBR], accE1[M_NBR];
    #pragma unroll
    for (int m = 0; m < M_NBR; ++m) { accE0[m] = 0.f; accE1[m] = 0.f; }
    for (int k = 0; k < EDGE; ++k) {
        const float we0 = We[(long)k * FD + f0];
        const float we1 = We[(long)k * FD + f1];
        #pragma unroll
        for (int m = 0; m < M_NBR; ++m) {
            const float v = e_s[m][k];
            accE0[m] = fmaf(v, we0, accE0[m]);
            accE1[m] = fmaf(v, we1, accE1[m]);
        }
    }

    // ---- inter = phi_c * phi_n * phi_e  -> LDS ----
    const float bn0 = bn[f0], bn1 = bn[f1];
    const float be0 = be[f0], be1 = be[f1];
    #pragma unroll
    for (int m = 0; m < M_NBR; ++m) {
        inter_s[m][f0] = accC0 * (accN0[m] + bn0) * (accE0[m] + be0);
        inter_s[m][f1] = accC1 * (accN1[m] + bn1) * (accE1[m] + be1);
    }
    __syncthreads();

    // ---- gate & mag GEMV phase ----
    float accG0[M_NBR], accG1[M_NBR], accM0[M_NBR], accM1[M_NBR];
    #pragma unroll
    for (int m = 0; m < M_NBR; ++m) {
        accG0[m] = 0.f; accG1[m] = 0.f; accM0[m] = 0.f; accM1[m] = 0.f;
    }
    for (int k0 = 0; k0 < FD; k0 += 4) {
        float wg0[4], wg1[4], wm0[4], wm1[4];
        #pragma unroll
        for (int j = 0; j < 4; ++j) {
            const float* wgp = Wg + (long)(k0 + j) * FD;
            const float* wmp = Wm + (long)(k0 + j) * FD;
            wg0[j] = wgp[f0]; wg1[j] = wgp[f1];
            wm0[j] = wmp[f0]; wm1[j] = wmp[f1];
        }
        #pragma unroll
        for (int m = 0; m < M_NBR; ++m) {
            const float4 iv4 = *(const float4*)(inter_s[m] + k0);
            const float iv[4] = {iv4.x, iv4.y, iv4.z, iv4.w};
            #pragma unroll
            for (int j = 0; j < 4; ++j) {
                accG0[m] = fmaf(iv[j], wg0[j], accG0[m]);
                accG1[m] = fmaf(iv[j], wg1[j], accG1[m]);
                accM0[m] = fmaf(iv[j], wm0[j], accM0[m]);
                accM1[m] = fmaf(iv[j], wm1[j], accM1[m]);
            }
        }
    }

    // ---- activation, sum over neighbors ----
    const float bg0 = bg[f0], bg1 = bg[f1];
    const float bm0 = bm[f0], bm1 = bm[f1];
    float s0 = 0.f, s1 = 0.f;
    #pragma unroll
    for (int m = 0; m < M_NBR; ++m) {
        s0 += sigmoid_f(accG0[m] + bg0) * softplus_f(accM0[m] + bm0);
        s1 += sigmoid_f(accG1[m] + bg1) * softplus_f(accM1[m] + bm1);
    }

    // ---- LayerNorm over the 128 features (64 lanes x 2) ----
    float sum = s0 + s1;
    float sumsq = s0 * s0 + s1 * s1;
    #pragma unroll
    for (int off = 32; off > 0; off >>= 1) {
        sum   += __shfl_xor(sum, off, 64);
        sumsq += __shfl_xor(sumsq, off, 64);
    }
    const float mu  = sum * (1.0f / FD);
    float var = sumsq * (1.0f / FD) - mu * mu;
    var = fmaxf(var, 0.0f);
    const float inv = rsqrtf(var + 1e-6f);
    const float y0 = (s0 - mu) * inv * lns[f0] + lnb[f0];
    const float y1 = (s1 - mu) * inv * lns[f1] + lnb[f1];
    x_out[(long)n * FD + f0] = xc_s[f0] + y0;
    x_out[(long)n * FD + f1] = xc_s[f1] + y1;
}

// ---------------- readout: softplus(x@Wh+bh)@Wo + bo, sum per crystal ----
__global__ __launch_bounds__(64) void readout_kernel(
    const float* __restrict__ x, const float* __restrict__ Wh,
    const float* __restrict__ bh, const float* __restrict__ Wo,
    const float* __restrict__ bo, float* __restrict__ out)
{
    __shared__ float row[FD];
    const int n = blockIdx.x;
    const int t = threadIdx.x;           // 0..63
    row[t] = x[(long)n * FD + t];
    row[t + 64] = x[(long)n * FD + t + 64];
    __syncthreads();

    float acc[4];
    #pragma unroll
    for (int j = 0; j < 4; ++j) acc[j] = bh[t + j * 64];

    for (int k0 = 0; k0 < FD; k0 += 4) {
        const float4 xv4 = *(const float4*)(row + k0);
        const float xv[4] = {xv4.x, xv4.y, xv4.z, xv4.w};
        #pragma unroll
        for (int kk = 0; kk < 4; ++kk) {
            const float* wp = Wh + (long)(k0 + kk) * HD;
            #pragma unroll
            for (int j = 0; j < 4; ++j)
                acc[j] = fmaf(xv[kk], wp[t + j * 64], acc[j]);
        }
    }

    float e = 0.f;
    #pragma unroll
    for (int j = 0; j < 4; ++j)
        e += softplus_f(acc[j]) * Wo[t + j * 64];

    #pragma unroll
    for (int off = 32; off > 0; off >>= 1)
        e += __shfl_xor(e, off, 64);

    if (t == 0) atomicAdd(&out[n / APC], e + bo[0]);
}

__global__ void zero_out_kernel(float* __restrict__ out) {
    if (threadIdx.x < NCRY) out[threadIdx.x] = 0.0f;
}

extern "C" void kernel_launch(void* const* d_in, const int* in_sizes, int n_in,
                              void* d_out, int out_size, void* d_ws, size_t ws_size,
                              hipStream_t stream) {
    const float* atom_fea = (const float*)d_in[0];
    const float* nbr_fea  = (const float*)d_in[1];
    const int*   nbr_idx  = (const int*)d_in[2];
    const float* W_embed  = (const float*)d_in[3];
    const float* b_embed  = (const float*)d_in[4];
    const float* W_center = (const float*)d_in[5];
    const float* b_center = (const float*)d_in[6];
    const float* W_nbr    = (const float*)d_in[7];
    const float* b_nbr    = (const float*)d_in[8];
    const float* W_edge   = (const float*)d_in[9];
    const float* b_edge   = (const float*)d_in[10];
    const float* W_gate   = (const float*)d_in[11];
    const float* b_gate   = (const float*)d_in[12];
    const float* W_mag    = (const float*)d_in[13];
    const float* b_mag    = (const float*)d_in[14];
    const float* ln_scale = (const float*)d_in[15];
    const float* ln_bias  = (const float*)d_in[16];
    const float* W_h      = (const float*)d_in[17];
    const float* b_h      = (const float*)d_in[18];
    const float* W_out    = (const float*)d_in[19];
    const float* b_out    = (const float*)d_in[20];

    float* out = (float*)d_out;
    float* xA = (float*)d_ws;                        // [N_TOT, FD]
    float* xB = xA + (size_t)N_TOT * FD;             // [N_TOT, FD]

    embed_kernel<<<N_TOT, 64, 0, stream>>>(atom_fea, W_embed, b_embed, xA);

    const float* xi = xA;
    float* xo = xB;
    for (int l = 0; l < 3; ++l) {
        conv_kernel<<<N_TOT, 64, 0, stream>>>(
            xi, xo, nbr_fea, nbr_idx,
            W_center + (size_t)l * FD * FD, b_center + (size_t)l * FD,
            W_nbr    + (size_t)l * FD * FD, b_nbr    + (size_t)l * FD,
            W_edge   + (size_t)l * EDGE * FD, b_edge + (size_t)l * FD,
            W_gate   + (size_t)l * FD * FD, b_gate   + (size_t)l * FD,
            W_mag    + (size_t)l * FD * FD, b_mag    + (size_t)l * FD,
            ln_scale + (size_t)l * FD, ln_bias + (size_t)l * FD);
        const float* tmp = xo; xo = (float*)xi; xi = tmp;
    }

    zero_out_kernel<<<1, 128, 0, stream>>>(out);
    readout_kernel<<<N_TOT, 64, 0, stream>>>(xi, W_h, b_h, W_out, b_out, out);
}

// Round 2
// 724.060 us; speedup vs baseline: 3.8856x; 3.8856x over previous
//
#include <hip/hip_runtime.h>
#include <math.h>

#define N_TOT 32768
#define M_NBR 12
#define ORIG  92
#define EDGE  41
#define FD    128
#define HD    256
#define APC   256
#define NCRY  128

#define STR   136          // inter_s row stride in bf16 (16B-aligned rows, low conflict)
#define WF_PER_LAYER 73728 // bf16 elems of swizzled weight frags per layer

typedef __attribute__((ext_vector_type(8))) short bf16x8;
typedef __attribute__((ext_vector_type(4))) float f32x4;

__device__ __forceinline__ short f2bf(float f) {
    union { float f; unsigned u; } v; v.f = f;
    unsigned r = v.u + 0x7fffu + ((v.u >> 16) & 1u);   // RNE
    return (short)(r >> 16);
}
__device__ __forceinline__ float bf2f(short s) {
    union { unsigned u; float f; } v; v.u = ((unsigned)(unsigned short)s) << 16;
    return v.f;
}
__device__ __forceinline__ float softplus_f(float x) {
    return fmaxf(x, 0.0f) + __logf(1.0f + __expf(-fabsf(x)));
}
__device__ __forceinline__ float sigmoid_f(float x) {
    return 1.0f / (1.0f + __expf(-x));
}

// ---------------- weight pre-swizzle into B-fragment order ----------------
// B-frag layout: for (kt, nt): lane l holds W[kt*32 + (l>>4)*8 + j][nt*16 + (l&15)], j=0..7
// stored at dst[((kt*8+nt)*64 + l)*8 + j]
__global__ __launch_bounds__(256) void swizzle_kernel(
    const float* __restrict__ Wc_all, const float* __restrict__ Wn_all,
    const float* __restrict__ We_all, const float* __restrict__ Wg_all,
    const float* __restrict__ Wm_all, short* __restrict__ dst_all)
{
    int gid = blockIdx.x * 256 + threadIdx.x;
    if (gid >= 3 * 9216) return;
    int layer = gid / 9216;
    int rem = gid - layer * 9216;
    short* dbase = dst_all + layer * WF_PER_LAYER;
    const float* W; short* dst; int K_real, fid;
    if (rem < 2048)      { W = Wc_all + layer * 16384; dst = dbase;         K_real = 128; fid = rem; }
    else if (rem < 4096) { W = Wn_all + layer * 16384; dst = dbase + 16384; K_real = 128; fid = rem - 2048; }
    else if (rem < 5120) { W = We_all + layer * 5248;  dst = dbase + 32768; K_real = 41;  fid = rem - 4096; }
    else if (rem < 7168) { W = Wg_all + layer * 16384; dst = dbase + 40960; K_real = 128; fid = rem - 5120; }
    else                 { W = Wm_all + layer * 16384; dst = dbase + 57344; K_real = 128; fid = rem - 7168; }
    int l = fid & 63, nt = (fid >> 6) & 7, kt = fid >> 9;
    int n = nt * 16 + (l & 15), kb = kt * 32 + (l >> 4) * 8;
    bf16x8 v;
    #pragma unroll
    for (int j = 0; j < 8; ++j) {
        int k = kb + j;
        v[j] = (k < K_real) ? f2bf(W[k * 128 + n]) : (short)0;
    }
    *(bf16x8*)(dst + fid * 8) = v;
}

// ---------------- embed: x = atom_fea @ W_embed + b_embed (fp32 + bf16 out) ----
__global__ __launch_bounds__(64) void embed_kernel(
    const float* __restrict__ atom_fea, const float* __restrict__ W,
    const float* __restrict__ b, float* __restrict__ x, short* __restrict__ xbf)
{
    __shared__ float row[ORIG];
    const int n = blockIdx.x;
    const int t = threadIdx.x;
    const float* af = atom_fea + (long)n * ORIG;
    if (t < ORIG) row[t] = af[t];
    if (t + 64 < ORIG) row[t + 64] = af[t + 64];
    __syncthreads();

    const int f0 = t, f1 = t + 64;
    float acc0 = b[f0], acc1 = b[f1];
    #pragma unroll 4
    for (int k = 0; k < ORIG; ++k) {
        const float xk = row[k];
        acc0 = fmaf(xk, W[k * FD + f0], acc0);
        acc1 = fmaf(xk, W[k * FD + f1], acc1);
    }
    x[(long)n * FD + f0] = acc0;
    x[(long)n * FD + f1] = acc1;
    xbf[(long)n * FD + f0] = f2bf(acc0);
    xbf[(long)n * FD + f1] = f2bf(acc1);
}

// ---------------- fused MFMA conv layer: 16 atoms / block, 4 waves ----------------
__global__ __launch_bounds__(256) void conv_mfma_kernel(
    const float* __restrict__ x_in, const short* __restrict__ xbf_in,
    float* __restrict__ x_out, short* __restrict__ xbf_out,
    const float* __restrict__ nbr_fea, const int* __restrict__ nbr_idx,
    const short* __restrict__ wf,
    const float* __restrict__ bc, const float* __restrict__ bn,
    const float* __restrict__ be, const float* __restrict__ bg,
    const float* __restrict__ bm,
    const float* __restrict__ lns, const float* __restrict__ lnb)
{
    __shared__ short inter_s[192 * STR];       // 52224 B; reused for p = gate*mag
    __shared__ float phic_s[16 * 132];         // 8448 B
    __shared__ int   idx_s[192];

    const int tid = threadIdx.x;
    const int w = tid >> 6, lane = tid & 63;
    const int q = lane >> 4, m = lane & 15;
    const int a0 = blockIdx.x * 16;
    const long r0 = (long)a0 * M_NBR;

    const short* Wc = wf;
    const short* Wn = wf + 16384;
    const short* We = wf + 32768;
    const short* Wg = wf + 40960;
    const short* Wm = wf + 57344;

    if (tid < 192) idx_s[tid] = nbr_idx[r0 + tid];

    // ---- phi_c = x(own) @ Wc + bc  (1 M-tile of 16 atoms; wave w does nt=2w,2w+1) ----
    {
        bf16x8 aC[4];
        #pragma unroll
        for (int kt = 0; kt < 4; ++kt)
            aC[kt] = *(const bf16x8*)(xbf_in + ((long)(a0 + m) << 7) + kt * 32 + q * 8);
        #pragma unroll
        for (int ii = 0; ii < 2; ++ii) {
            const int nt = w * 2 + ii;
            f32x4 C = {0.f, 0.f, 0.f, 0.f};
            #pragma unroll
            for (int kt = 0; kt < 4; ++kt)
                C = __builtin_amdgcn_mfma_f32_16x16x32_bf16(
                        aC[kt], *(const bf16x8*)(Wc + ((kt * 8 + nt) * 64 + lane) * 8), C, 0, 0, 0);
            const int col = nt * 16 + m;
            const float bcv = bc[col];
            #pragma unroll
            for (int r = 0; r < 4; ++r)
                phic_s[(q * 4 + r) * 132 + col] = C[r] + bcv;
        }
    }
    __syncthreads();   // idx_s + phic_s visible to all

    // ---- A-fragments: gathered neighbor rows (bf16, direct from global) ----
    bf16x8 aN[3][4];
    #pragma unroll
    for (int i = 0; i < 3; ++i) {
        const int row = (w * 3 + i) * 16 + m;
        const long g = (long)idx_s[row] << 7;
        #pragma unroll
        for (int kt = 0; kt < 4; ++kt)
            aN[i][kt] = *(const bf16x8*)(xbf_in + g + kt * 32 + q * 8);
    }
    // ---- A-fragments: edge features (fp32 -> bf16, K=41 padded to 64) ----
    bf16x8 aE[3][2];
    #pragma unroll
    for (int i = 0; i < 3; ++i) {
        const int row = (w * 3 + i) * 16 + m;
        const float* ep = nbr_fea + (r0 + row) * EDGE;
        bf16x8 e0, e1;
        #pragma unroll
        for (int j = 0; j < 8; ++j) e0[j] = f2bf(ep[q * 8 + j]);
        #pragma unroll
        for (int j = 0; j < 8; ++j) e1[j] = 0;
        if (q == 0) {
            #pragma unroll
            for (int j = 0; j < 8; ++j) e1[j] = f2bf(ep[32 + j]);
        } else if (q == 1) {
            e1[0] = f2bf(ep[40]);
        }
        aE[i][0] = e0; aE[i][1] = e1;
    }

    // ---- phi_n & phi_e GEMMs -> inter = phi_c * phi_n * phi_e (bf16 in LDS) ----
    #pragma unroll
    for (int nt = 0; nt < 8; ++nt) {
        f32x4 Cn[3], Ce[3];
        #pragma unroll
        for (int i = 0; i < 3; ++i) { Cn[i] = (f32x4){0.f,0.f,0.f,0.f}; Ce[i] = (f32x4){0.f,0.f,0.f,0.f}; }
        #pragma unroll
        for (int kt = 0; kt < 4; ++kt) {
            const bf16x8 bfr = *(const bf16x8*)(Wn + ((kt * 8 + nt) * 64 + lane) * 8);
            #pragma unroll
            for (int i = 0; i < 3; ++i)
                Cn[i] = __builtin_amdgcn_mfma_f32_16x16x32_bf16(aN[i][kt], bfr, Cn[i], 0, 0, 0);
        }
        #pragma unroll
        for (int kt = 0; kt < 2; ++kt) {
            const bf16x8 efr = *(const bf16x8*)(We + ((kt * 8 + nt) * 64 + lane) * 8);
            #pragma unroll
            for (int i = 0; i < 3; ++i)
                Ce[i] = __builtin_amdgcn_mfma_f32_16x16x32_bf16(aE[i][kt], efr, Ce[i], 0, 0, 0);
        }
        const int col = nt * 16 + m;
        const float bnv = bn[col], bev = be[col];
        #pragma unroll
        for (int i = 0; i < 3; ++i) {
            const int rb = (w * 3 + i) * 16 + q * 4;
            #pragma unroll
            for (int r = 0; r < 4; ++r) {
                const int row = rb + r;
                const int atom = row / 12;
                const float iv = phic_s[atom * 132 + col] * (Cn[i][r] + bnv) * (Ce[i][r] + bev);
                inter_s[row * STR + col] = f2bf(iv);
            }
        }
    }

    // ---- inter A-fragments (wave-private rows; in-wave DS ordering suffices) ----
    bf16x8 aI[3][4];
    #pragma unroll
    for (int i = 0; i < 3; ++i) {
        const int row = (w * 3 + i) * 16 + m;
        #pragma unroll
        for (int kt = 0; kt < 4; ++kt)
            aI[i][kt] = *(const bf16x8*)(inter_s + row * STR + kt * 32 + q * 8);
    }

    // ---- gate & mag GEMMs -> p = sigmoid(gate) * softplus(mag) (overwrite LDS) ----
    #pragma unroll
    for (int nt = 0; nt < 8; ++nt) {
        f32x4 Cg[3], Cm[3];
        #pragma unroll
        for (int i = 0; i < 3; ++i) { Cg[i] = (f32x4){0.f,0.f,0.f,0.f}; Cm[i] = (f32x4){0.f,0.f,0.f,0.f}; }
        #pragma unroll
        for (int kt = 0; kt < 4; ++kt) {
            const bf16x8 gfr = *(const bf16x8*)(Wg + ((kt * 8 + nt) * 64 + lane) * 8);
            const bf16x8 mfr = *(const bf16x8*)(Wm + ((kt * 8 + nt) * 64 + lane) * 8);
            #pragma unroll
            for (int i = 0; i < 3; ++i) {
                Cg[i] = __builtin_amdgcn_mfma_f32_16x16x32_bf16(aI[i][kt], gfr, Cg[i], 0, 0, 0);
                Cm[i] = __builtin_amdgcn_mfma_f32_16x16x32_bf16(aI[i][kt], mfr, Cm[i], 0, 0, 0);
            }
        }
        const int col = nt * 16 + m;
        const float bgv = bg[col], bmv = bm[col];
        #pragma unroll
        for (int i = 0; i < 3; ++i) {
            const int rb = (w * 3 + i) * 16 + q * 4;
            #pragma unroll
            for (int r = 0; r < 4; ++r) {
                const float g = sigmoid_f(Cg[i][r] + bgv);
                const float s = softplus_f(Cm[i][r] + bmv);
                inter_s[(rb + r) * STR + col] = f2bf(g * s);
            }
        }
    }
    __syncthreads();   // all p values visible

    // ---- neighbor-sum + LayerNorm + residual; thread t: atom=t>>4, 8 cols ----
    {
        const int a = tid >> 4;
        const int cg = tid & 15;
        float s8[8];
        #pragma unroll
        for (int j = 0; j < 8; ++j) s8[j] = 0.f;
        #pragma unroll
        for (int nb = 0; nb < 12; ++nb) {
            const bf16x8 p = *(const bf16x8*)(inter_s + (a * 12 + nb) * STR + cg * 8);
            #pragma unroll
            for (int j = 0; j < 8; ++j) s8[j] += bf2f(p[j]);
        }
        float lsum = 0.f, lsq = 0.f;
        #pragma unroll
        for (int j = 0; j < 8; ++j) { lsum += s8[j]; lsq += s8[j] * s8[j]; }
        #pragma unroll
        for (int off = 1; off < 16; off <<= 1) {
            lsum += __shfl_xor(lsum, off, 64);
            lsq  += __shfl_xor(lsq,  off, 64);
        }
        const float mu = lsum * (1.0f / FD);
        float var = lsq * (1.0f / FD) - mu * mu;
        var = fmaxf(var, 0.0f);
        const float inv = rsqrtf(var + 1e-6f);
        const long xb = ((long)(a0 + a) << 7) + cg * 8;
        float o[8]; bf16x8 ob;
        #pragma unroll
        for (int j = 0; j < 8; ++j) {
            const int col = cg * 8 + j;
            const float y = (s8[j] - mu) * inv * lns[col] + lnb[col];
            const float v = x_in[xb + j] + y;
            o[j] = v; ob[j] = f2bf(v);
        }
        *(float4*)(x_out + xb)     = make_float4(o[0], o[1], o[2], o[3]);
        *(float4*)(x_out + xb + 4) = make_float4(o[4], o[5], o[6], o[7]);
        *(bf16x8*)(xbf_out + xb)   = ob;
    }
}

// ---------------- readout ----------------
__global__ __launch_bounds__(64) void readout_kernel(
    const float* __restrict__ x, const float* __restrict__ Wh,
    const float* __restrict__ bh, const float* __restrict__ Wo,
    const float* __restrict__ bo, float* __restrict__ out)
{
    __shared__ float row[FD];
    const int n = blockIdx.x;
    const int t = threadIdx.x;
    row[t] = x[(long)n * FD + t];
    row[t + 64] = x[(long)n * FD + t + 64];
    __syncthreads();

    float acc[4];
    #pragma unroll
    for (int j = 0; j < 4; ++j) acc[j] = bh[t + j * 64];

    for (int k0 = 0; k0 < FD; k0 += 4) {
        const float4 xv4 = *(const float4*)(row + k0);
        const float xv[4] = {xv4.x, xv4.y, xv4.z, xv4.w};
        #pragma unroll
        for (int kk = 0; kk < 4; ++kk) {
            const float* wp = Wh + (long)(k0 + kk) * HD;
            #pragma unroll
            for (int j = 0; j < 4; ++j)
                acc[j] = fmaf(xv[kk], wp[t + j * 64], acc[j]);
        }
    }
    float e = 0.f;
    #pragma unroll
    for (int j = 0; j < 4; ++j)
        e += softplus_f(acc[j]) * Wo[t + j * 64];
    #pragma unroll
    for (int off = 32; off > 0; off >>= 1)
        e += __shfl_xor(e, off, 64);
    if (t == 0) atomicAdd(&out[n / APC], e + bo[0]);
}

__global__ void zero_out_kernel(float* __restrict__ out) {
    if (threadIdx.x < NCRY) out[threadIdx.x] = 0.0f;
}

extern "C" void kernel_launch(void* const* d_in, const int* in_sizes, int n_in,
                              void* d_out, int out_size, void* d_ws, size_t ws_size,
                              hipStream_t stream) {
    const float* atom_fea = (const float*)d_in[0];
    const float* nbr_fea  = (const float*)d_in[1];
    const int*   nbr_idx  = (const int*)d_in[2];
    const float* W_embed  = (const float*)d_in[3];
    const float* b_embed  = (const float*)d_in[4];
    const float* W_center = (const float*)d_in[5];
    const float* b_center = (const float*)d_in[6];
    const float* W_nbr    = (const float*)d_in[7];
    const float* b_nbr    = (const float*)d_in[8];
    const float* W_edge   = (const float*)d_in[9];
    const float* b_edge   = (const float*)d_in[10];
    const float* W_gate   = (const float*)d_in[11];
    const float* b_gate   = (const float*)d_in[12];
    const float* W_mag    = (const float*)d_in[13];
    const float* b_mag    = (const float*)d_in[14];
    const float* ln_scale = (const float*)d_in[15];
    const float* ln_bias  = (const float*)d_in[16];
    const float* W_h      = (const float*)d_in[17];
    const float* b_h      = (const float*)d_in[18];
    const float* W_out    = (const float*)d_in[19];
    const float* b_out    = (const float*)d_in[20];

    float* out = (float*)d_out;
    const size_t NX = (size_t)N_TOT * FD;
    float* xA = (float*)d_ws;
    float* xB = xA + NX;
    short* xbfA = (short*)(xB + NX);
    short* xbfB = xbfA + NX;
    short* wfrag = xbfB + NX;

    swizzle_kernel<<<108, 256, 0, stream>>>(W_center, W_nbr, W_edge, W_gate, W_mag, wfrag);
    embed_kernel<<<N_TOT, 64, 0, stream>>>(atom_fea, W_embed, b_embed, xA, xbfA);

    const float* xi = xA; float* xo = xB;
    const short* xbi = xbfA; short* xbo = xbfB;
    for (int l = 0; l < 3; ++l) {
        conv_mfma_kernel<<<N_TOT / 16, 256, 0, stream>>>(
            xi, xbi, xo, xbo, nbr_fea, nbr_idx,
            wfrag + (size_t)l * WF_PER_LAYER,
            b_center + (size_t)l * FD, b_nbr + (size_t)l * FD,
            b_edge + (size_t)l * FD, b_gate + (size_t)l * FD,
            b_mag + (size_t)l * FD,
            ln_scale + (size_t)l * FD, ln_bias + (size_t)l * FD);
        const float* tf = xo; xo = (float*)xi; xi = tf;
        const short* tb = xbo; xbo = (short*)xbi; xbi = tb;
    }

    zero_out_kernel<<<1, 128, 0, stream>>>(out);
    readout_kernel<<<N_TOT, 64, 0, stream>>>(xi, W_h, b_h, W_out, b_out, out);
}

// Round 3
// 465.845 us; speedup vs baseline: 6.0394x; 1.5543x over previous
//
#include <hip/hip_runtime.h>
#include <math.h>

#define N_TOT 32768
#define M_NBR 12
#define ORIG  92
#define EDGE  41
#define FD    128
#define HD    256
#define APC   256
#define NCRY  128

#define STR   136          // inter_s row stride in bf16
#define WF_PER_LAYER 73728 // bf16 elems of swizzled conv weight frags per layer
#define WF_EMBED     12288 // 3 ktiles x 8 ntiles x 64 x 8
#define WF_H         32768 // 4 ktiles x 16 ntiles x 64 x 8

typedef __attribute__((ext_vector_type(8))) short bf16x8;
typedef __attribute__((ext_vector_type(4))) float f32x4;

__device__ __forceinline__ short f2bf(float f) {
    union { float f; unsigned u; } v; v.f = f;
    unsigned r = v.u + 0x7fffu + ((v.u >> 16) & 1u);   // RNE
    return (short)(r >> 16);
}
__device__ __forceinline__ float bf2f(short s) {
    union { unsigned u; float f; } v; v.u = ((unsigned)(unsigned short)s) << 16;
    return v.f;
}
__device__ __forceinline__ float softplus_f(float x) {
    return fmaxf(x, 0.0f) + __logf(1.0f + __expf(-fabsf(x)));
}
__device__ __forceinline__ float sigmoid_f(float x) {
    return 1.0f / (1.0f + __expf(-x));
}

// ---------------- weight pre-swizzle into B-fragment order ----------------
// B-frag: for (kt,nt): lane l holds W[kt*32 + (l>>4)*8 + j][nt*16 + (l&15)], j=0..7
__global__ __launch_bounds__(256) void swizzle_kernel(
    const float* __restrict__ Wc_all, const float* __restrict__ Wn_all,
    const float* __restrict__ We_all, const float* __restrict__ Wg_all,
    const float* __restrict__ Wm_all, const float* __restrict__ W_embed,
    const float* __restrict__ W_h, short* __restrict__ dst_all)
{
    int gid = blockIdx.x * 256 + threadIdx.x;
    if (gid >= 33280) return;
    const float* W; short* dst; int K_real, fid, stride, l, nt, kt;
    if (gid < 27648) {
        int layer = gid / 9216;
        int rem = gid - layer * 9216;
        short* dbase = dst_all + layer * WF_PER_LAYER;
        if (rem < 2048)      { W = Wc_all + layer * 16384; dst = dbase;         K_real = 128; fid = rem; }
        else if (rem < 4096) { W = Wn_all + layer * 16384; dst = dbase + 16384; K_real = 128; fid = rem - 2048; }
        else if (rem < 5120) { W = We_all + layer * 5248;  dst = dbase + 32768; K_real = 41;  fid = rem - 4096; }
        else if (rem < 7168) { W = Wg_all + layer * 16384; dst = dbase + 40960; K_real = 128; fid = rem - 5120; }
        else                 { W = Wm_all + layer * 16384; dst = dbase + 57344; K_real = 128; fid = rem - 7168; }
        stride = 128; l = fid & 63; nt = (fid >> 6) & 7; kt = fid >> 9;
    } else if (gid < 29184) {
        fid = gid - 27648;
        W = W_embed; dst = dst_all + 3 * WF_PER_LAYER; K_real = ORIG; stride = 128;
        l = fid & 63; nt = (fid >> 6) & 7; kt = fid >> 9;
    } else {
        fid = gid - 29184;
        W = W_h; dst = dst_all + 3 * WF_PER_LAYER + WF_EMBED; K_real = 128; stride = 256;
        l = fid & 63; nt = (fid >> 6) & 15; kt = fid >> 10;
    }
    int n = nt * 16 + (l & 15), kb = kt * 32 + (l >> 4) * 8;
    bf16x8 v;
    #pragma unroll
    for (int j = 0; j < 8; ++j) {
        int k = kb + j;
        v[j] = (k < K_real) ? f2bf(W[k * stride + n]) : (short)0;
    }
    *(bf16x8*)(dst + fid * 8) = v;
}

// ---------------- embed MFMA: 64 atoms/block, 4 waves ----------------
__global__ __launch_bounds__(256) void embed_mfma_kernel(
    const float* __restrict__ atom_fea, const short* __restrict__ wef,
    const float* __restrict__ b, float* __restrict__ x, short* __restrict__ xbf)
{
    const int tid = threadIdx.x;
    const int w = tid >> 6, lane = tid & 63;
    const int q = lane >> 4, m = lane & 15;
    const int a0 = blockIdx.x * 64;
    const int arow = a0 + w * 16 + m;

    // A-fragments: atom_fea row (fp32 -> bf16), K padded 92 -> 96
    bf16x8 aA[3];
    const float* ap = atom_fea + (long)arow * ORIG;
    #pragma unroll
    for (int kt = 0; kt < 3; ++kt) {
        const int kb = kt * 32 + q * 8;
        bf16x8 v;
        if (kb + 7 < ORIG) {
            const float4 u0 = *(const float4*)(ap + kb);
            const float4 u1 = *(const float4*)(ap + kb + 4);
            v[0]=f2bf(u0.x); v[1]=f2bf(u0.y); v[2]=f2bf(u0.z); v[3]=f2bf(u0.w);
            v[4]=f2bf(u1.x); v[5]=f2bf(u1.y); v[6]=f2bf(u1.z); v[7]=f2bf(u1.w);
        } else {
            #pragma unroll
            for (int j = 0; j < 8; ++j) {
                const int k = kb + j;
                v[j] = (k < ORIG) ? f2bf(ap[k]) : (short)0;
            }
        }
        aA[kt] = v;
    }

    #pragma unroll
    for (int nt = 0; nt < 8; ++nt) {
        f32x4 C = {0.f, 0.f, 0.f, 0.f};
        #pragma unroll
        for (int kt = 0; kt < 3; ++kt)
            C = __builtin_amdgcn_mfma_f32_16x16x32_bf16(
                    aA[kt], *(const bf16x8*)(wef + ((kt * 8 + nt) * 64 + lane) * 8), C, 0, 0, 0);
        const int col = nt * 16 + m;
        const float bv = b[col];
        #pragma unroll
        for (int r = 0; r < 4; ++r) {
            const long n = a0 + w * 16 + q * 4 + r;
            const float val = C[r] + bv;
            x[n * FD + col] = val;
            xbf[n * FD + col] = f2bf(val);
        }
    }
}

// ---------------- fused MFMA conv layer: 16 atoms / block, 4 waves ----------------
__global__ __launch_bounds__(256) void conv_mfma_kernel(
    const float* __restrict__ x_in, const short* __restrict__ xbf_in,
    float* __restrict__ x_out, short* __restrict__ xbf_out,
    const float* __restrict__ nbr_fea, const int* __restrict__ nbr_idx,
    const short* __restrict__ wf,
    const float* __restrict__ bc, const float* __restrict__ bn,
    const float* __restrict__ be, const float* __restrict__ bg,
    const float* __restrict__ bm,
    const float* __restrict__ lns, const float* __restrict__ lnb)
{
    __shared__ short inter_s[192 * STR];
    __shared__ float phic_s[16 * 132];
    __shared__ int   idx_s[192];

    const int tid = threadIdx.x;
    const int w = tid >> 6, lane = tid & 63;
    const int q = lane >> 4, m = lane & 15;
    const int a0 = blockIdx.x * 16;
    const long r0 = (long)a0 * M_NBR;

    const short* Wc = wf;
    const short* Wn = wf + 16384;
    const short* We = wf + 32768;
    const short* Wg = wf + 40960;
    const short* Wm = wf + 57344;

    if (tid < 192) idx_s[tid] = nbr_idx[r0 + tid];

    {
        bf16x8 aC[4];
        #pragma unroll
        for (int kt = 0; kt < 4; ++kt)
            aC[kt] = *(const bf16x8*)(xbf_in + ((long)(a0 + m) << 7) + kt * 32 + q * 8);
        #pragma unroll
        for (int ii = 0; ii < 2; ++ii) {
            const int nt = w * 2 + ii;
            f32x4 C = {0.f, 0.f, 0.f, 0.f};
            #pragma unroll
            for (int kt = 0; kt < 4; ++kt)
                C = __builtin_amdgcn_mfma_f32_16x16x32_bf16(
                        aC[kt], *(const bf16x8*)(Wc + ((kt * 8 + nt) * 64 + lane) * 8), C, 0, 0, 0);
            const int col = nt * 16 + m;
            const float bcv = bc[col];
            #pragma unroll
            for (int r = 0; r < 4; ++r)
                phic_s[(q * 4 + r) * 132 + col] = C[r] + bcv;
        }
    }
    __syncthreads();

    bf16x8 aN[3][4];
    #pragma unroll
    for (int i = 0; i < 3; ++i) {
        const int row = (w * 3 + i) * 16 + m;
        const long g = (long)idx_s[row] << 7;
        #pragma unroll
        for (int kt = 0; kt < 4; ++kt)
            aN[i][kt] = *(const bf16x8*)(xbf_in + g + kt * 32 + q * 8);
    }
    bf16x8 aE[3][2];
    #pragma unroll
    for (int i = 0; i < 3; ++i) {
        const int row = (w * 3 + i) * 16 + m;
        const float* ep = nbr_fea + (r0 + row) * EDGE;
        bf16x8 e0, e1;
        #pragma unroll
        for (int j = 0; j < 8; ++j) e0[j] = f2bf(ep[q * 8 + j]);
        #pragma unroll
        for (int j = 0; j < 8; ++j) e1[j] = 0;
        if (q == 0) {
            #pragma unroll
            for (int j = 0; j < 8; ++j) e1[j] = f2bf(ep[32 + j]);
        } else if (q == 1) {
            e1[0] = f2bf(ep[40]);
        }
        aE[i][0] = e0; aE[i][1] = e1;
    }

    #pragma unroll
    for (int nt = 0; nt < 8; ++nt) {
        f32x4 Cn[3], Ce[3];
        #pragma unroll
        for (int i = 0; i < 3; ++i) { Cn[i] = (f32x4){0.f,0.f,0.f,0.f}; Ce[i] = (f32x4){0.f,0.f,0.f,0.f}; }
        #pragma unroll
        for (int kt = 0; kt < 4; ++kt) {
            const bf16x8 bfr = *(const bf16x8*)(Wn + ((kt * 8 + nt) * 64 + lane) * 8);
            #pragma unroll
            for (int i = 0; i < 3; ++i)
                Cn[i] = __builtin_amdgcn_mfma_f32_16x16x32_bf16(aN[i][kt], bfr, Cn[i], 0, 0, 0);
        }
        #pragma unroll
        for (int kt = 0; kt < 2; ++kt) {
            const bf16x8 efr = *(const bf16x8*)(We + ((kt * 8 + nt) * 64 + lane) * 8);
            #pragma unroll
            for (int i = 0; i < 3; ++i)
                Ce[i] = __builtin_amdgcn_mfma_f32_16x16x32_bf16(aE[i][kt], efr, Ce[i], 0, 0, 0);
        }
        const int col = nt * 16 + m;
        const float bnv = bn[col], bev = be[col];
        #pragma unroll
        for (int i = 0; i < 3; ++i) {
            const int rb = (w * 3 + i) * 16 + q * 4;
            #pragma unroll
            for (int r = 0; r < 4; ++r) {
                const int row = rb + r;
                const int atom = row / 12;
                const float iv = phic_s[atom * 132 + col] * (Cn[i][r] + bnv) * (Ce[i][r] + bev);
                inter_s[row * STR + col] = f2bf(iv);
            }
        }
    }

    bf16x8 aI[3][4];
    #pragma unroll
    for (int i = 0; i < 3; ++i) {
        const int row = (w * 3 + i) * 16 + m;
        #pragma unroll
        for (int kt = 0; kt < 4; ++kt)
            aI[i][kt] = *(const bf16x8*)(inter_s + row * STR + kt * 32 + q * 8);
    }

    #pragma unroll
    for (int nt = 0; nt < 8; ++nt) {
        f32x4 Cg[3], Cm[3];
        #pragma unroll
        for (int i = 0; i < 3; ++i) { Cg[i] = (f32x4){0.f,0.f,0.f,0.f}; Cm[i] = (f32x4){0.f,0.f,0.f,0.f}; }
        #pragma unroll
        for (int kt = 0; kt < 4; ++kt) {
            const bf16x8 gfr = *(const bf16x8*)(Wg + ((kt * 8 + nt) * 64 + lane) * 8);
            const bf16x8 mfr = *(const bf16x8*)(Wm + ((kt * 8 + nt) * 64 + lane) * 8);
            #pragma unroll
            for (int i = 0; i < 3; ++i) {
                Cg[i] = __builtin_amdgcn_mfma_f32_16x16x32_bf16(aI[i][kt], gfr, Cg[i], 0, 0, 0);
                Cm[i] = __builtin_amdgcn_mfma_f32_16x16x32_bf16(aI[i][kt], mfr, Cm[i], 0, 0, 0);
            }
        }
        const int col = nt * 16 + m;
        const float bgv = bg[col], bmv = bm[col];
        #pragma unroll
        for (int i = 0; i < 3; ++i) {
            const int rb = (w * 3 + i) * 16 + q * 4;
            #pragma unroll
            for (int r = 0; r < 4; ++r) {
                const float g = sigmoid_f(Cg[i][r] + bgv);
                const float s = softplus_f(Cm[i][r] + bmv);
                inter_s[(rb + r) * STR + col] = f2bf(g * s);
            }
        }
    }
    __syncthreads();

    {
        const int a = tid >> 4;
        const int cg = tid & 15;
        float s8[8];
        #pragma unroll
        for (int j = 0; j < 8; ++j) s8[j] = 0.f;
        #pragma unroll
        for (int nb = 0; nb < 12; ++nb) {
            const bf16x8 p = *(const bf16x8*)(inter_s + (a * 12 + nb) * STR + cg * 8);
            #pragma unroll
            for (int j = 0; j < 8; ++j) s8[j] += bf2f(p[j]);
        }
        float lsum = 0.f, lsq = 0.f;
        #pragma unroll
        for (int j = 0; j < 8; ++j) { lsum += s8[j]; lsq += s8[j] * s8[j]; }
        #pragma unroll
        for (int off = 1; off < 16; off <<= 1) {
            lsum += __shfl_xor(lsum, off, 64);
            lsq  += __shfl_xor(lsq,  off, 64);
        }
        const float mu = lsum * (1.0f / FD);
        float var = lsq * (1.0f / FD) - mu * mu;
        var = fmaxf(var, 0.0f);
        const float inv = rsqrtf(var + 1e-6f);
        const long xb = ((long)(a0 + a) << 7) + cg * 8;
        float o[8]; bf16x8 ob;
        #pragma unroll
        for (int j = 0; j < 8; ++j) {
            const int col = cg * 8 + j;
            const float y = (s8[j] - mu) * inv * lns[col] + lnb[col];
            const float v = x_in[xb + j] + y;
            o[j] = v; ob[j] = f2bf(v);
        }
        *(float4*)(x_out + xb)     = make_float4(o[0], o[1], o[2], o[3]);
        *(float4*)(x_out + xb + 4) = make_float4(o[4], o[5], o[6], o[7]);
        *(bf16x8*)(xbf_out + xb)   = ob;
    }
}

// ---------------- readout MFMA: 64 atoms/block, 4 waves ----------------
__global__ __launch_bounds__(256) void readout_mfma_kernel(
    const short* __restrict__ xbf, const short* __restrict__ whf,
    const float* __restrict__ bh, const float* __restrict__ Wo,
    const float* __restrict__ bo, float* __restrict__ out)
{
    const int tid = threadIdx.x;
    const int w = tid >> 6, lane = tid & 63;
    const int q = lane >> 4, m = lane & 15;
    const int a0 = blockIdx.x * 64;
    const int arow = a0 + w * 16 + m;

    bf16x8 aX[4];
    #pragma unroll
    for (int kt = 0; kt < 4; ++kt)
        aX[kt] = *(const bf16x8*)(xbf + ((long)arow << 7) + kt * 32 + q * 8);

    float e[4] = {0.f, 0.f, 0.f, 0.f};
    #pragma unroll
    for (int nt = 0; nt < 16; ++nt) {
        f32x4 C = {0.f, 0.f, 0.f, 0.f};
        #pragma unroll
        for (int kt = 0; kt < 4; ++kt)
            C = __builtin_amdgcn_mfma_f32_16x16x32_bf16(
                    aX[kt], *(const bf16x8*)(whf + ((kt * 16 + nt) * 64 + lane) * 8), C, 0, 0, 0);
        const int col = nt * 16 + m;
        const float bhv = bh[col], wov = Wo[col];
        #pragma unroll
        for (int r = 0; r < 4; ++r)
            e[r] += softplus_f(C[r] + bhv) * wov;
    }
    float esum = e[0] + e[1] + e[2] + e[3];
    #pragma unroll
    for (int off = 32; off > 0; off >>= 1)
        esum += __shfl_xor(esum, off, 64);
    if (lane == 0)
        atomicAdd(&out[a0 / APC], esum + 16.0f * bo[0]);
}

__global__ void zero_out_kernel(float* __restrict__ out) {
    if (threadIdx.x < NCRY) out[threadIdx.x] = 0.0f;
}

extern "C" void kernel_launch(void* const* d_in, const int* in_sizes, int n_in,
                              void* d_out, int out_size, void* d_ws, size_t ws_size,
                              hipStream_t stream) {
    const float* atom_fea = (const float*)d_in[0];
    const float* nbr_fea  = (const float*)d_in[1];
    const int*   nbr_idx  = (const int*)d_in[2];
    const float* W_embed  = (const float*)d_in[3];
    const float* b_embed  = (const float*)d_in[4];
    const float* W_center = (const float*)d_in[5];
    const float* b_center = (const float*)d_in[6];
    const float* W_nbr    = (const float*)d_in[7];
    const float* b_nbr    = (const float*)d_in[8];
    const float* W_edge   = (const float*)d_in[9];
    const float* b_edge   = (const float*)d_in[10];
    const float* W_gate   = (const float*)d_in[11];
    const float* b_gate   = (const float*)d_in[12];
    const float* W_mag    = (const float*)d_in[13];
    const float* b_mag    = (const float*)d_in[14];
    const float* ln_scale = (const float*)d_in[15];
    const float* ln_bias  = (const float*)d_in[16];
    const float* W_h      = (const float*)d_in[17];
    const float* b_h      = (const float*)d_in[18];
    const float* W_out    = (const float*)d_in[19];
    const float* b_out    = (const float*)d_in[20];

    float* out = (float*)d_out;
    const size_t NX = (size_t)N_TOT * FD;
    float* xA = (float*)d_ws;
    float* xB = xA + NX;
    short* xbfA = (short*)(xB + NX);
    short* xbfB = xbfA + NX;
    short* wfrag = xbfB + NX;

    swizzle_kernel<<<130, 256, 0, stream>>>(W_center, W_nbr, W_edge, W_gate, W_mag,
                                            W_embed, W_h, wfrag);
    embed_mfma_kernel<<<N_TOT / 64, 256, 0, stream>>>(
        atom_fea, wfrag + 3 * WF_PER_LAYER, b_embed, xA, xbfA);

    const float* xi = xA; float* xo = xB;
    const short* xbi = xbfA; short* xbo = xbfB;
    for (int l = 0; l < 3; ++l) {
        conv_mfma_kernel<<<N_TOT / 16, 256, 0, stream>>>(
            xi, xbi, xo, xbo, nbr_fea, nbr_idx,
            wfrag + (size_t)l * WF_PER_LAYER,
            b_center + (size_t)l * FD, b_nbr + (size_t)l * FD,
            b_edge + (size_t)l * FD, b_gate + (size_t)l * FD,
            b_mag + (size_t)l * FD,
            ln_scale + (size_t)l * FD, ln_bias + (size_t)l * FD);
        const float* tf = xo; xo = (float*)xi; xi = tf;
        const short* tb = xbo; xbo = (short*)xbi; xbi = tb;
    }

    zero_out_kernel<<<1, 128, 0, stream>>>(out);
    readout_mfma_kernel<<<N_TOT / 64, 256, 0, stream>>>(
        xbi, wfrag + 3 * WF_PER_LAYER + WF_EMBED, b_h, W_out, b_out, out);
}